// Round 7
// baseline (3118.830 us; speedup 1.0000x reference)
//
#include <hip/hip_runtime.h>
#include <math.h>

#define B_ 32
#define S_ 256
#define H_ 2048
#define NH_ 16
#define HD_ 128
#define M_ (B_*S_)
#define K_ H_

typedef unsigned short u16;
typedef unsigned int   u32;
typedef _Float16 half8 __attribute__((ext_vector_type(8)));   // 8 fp16 (4 VGPRs) MFMA A/B frag
typedef __attribute__((ext_vector_type(8))) unsigned short ushort8;
typedef __attribute__((ext_vector_type(4))) float  floatx4;   // MFMA C/D frag

typedef __attribute__((address_space(3))) u32 lds_u32;
typedef __attribute__((address_space(1))) const u32 glb_u32;

__device__ __forceinline__ u16 f2h(float f) {
    _Float16 h = (_Float16)f;          // v_cvt_f16_f32, RNE
    u16 r; __builtin_memcpy(&r, &h, 2); return r;
}
__device__ __forceinline__ float h2f(u16 u) {
    _Float16 h; __builtin_memcpy(&h, &u, 2); return (float)h;
}
// async 16B global->LDS; lds addr must be wave-uniform base (+ lane*16 implicit)
__device__ __forceinline__ void gll16(const u16* g, u16* l) {
    __builtin_amdgcn_global_load_lds((glb_u32*)g, (lds_u32*)l, 16, 0, 0);
}

// ---------------------------------------------------------------------------
// fp32 -> fp16 (RNE)
// ---------------------------------------------------------------------------
__global__ __launch_bounds__(256) void cvt16(const float* __restrict__ x,
    u16* __restrict__ o, int n4)
{
    int i = blockIdx.x * 256 + threadIdx.x;
    if (i >= n4) return;
    float4 v = ((const float4*)x)[i];
    ((ushort4*)o)[i] = make_ushort4(f2h(v.x), f2h(v.y), f2h(v.z), f2h(v.w));
}

// ---------------------------------------------------------------------------
// C = A @ B^T, single-pass fp16 MFMA, fp32 acc.
// 256x256 tile, BK=32, 512 thr = 8 waves (2Mx4N), wave tile 128x64.
// Round-5 verified schedule (bulk frag reads, depth-2 counted-vmcnt dbuf):
// step t restages buf[cur] with tile t+2 after lgkm(0)+barrier; step-end waits
// vmcnt(4) (tile t+1 landed, t+2 in flight); never drains to 0 mid-loop.
// KEY CHANGE vs r6: LDS back to 64 KiB double-buffer (not 96 KiB triple) so
// TWO blocks are resident per CU, and grid 768 (fused QKV) actually supplies
// them.  r5 had this kernel at grid 256 = 1 block/CU available; the
// 256-tile x 2-resident cell was never tested.  Cross-block wave overlap
// covers the per-step rendezvous that no intra-block schedule has beaten.
// LDS plane-major: chunk (row,kc) at slot kc*256+row -> conflict-free b128
// frag reads + gll16-linear staging.  T1: bijective XCD swizzle.
// mode 0: fused QKV, N=6144, fp16 out, n>>11 selects Q/K/V plane (contiguous,
//         16777216 u16 apart), head-major [B,NH,S,HD].
// mode 1: fp32 [M,2048].
// ---------------------------------------------------------------------------
__global__ __launch_bounds__(512, 4) void gemm_f16(
    const u16* __restrict__ A, const u16* __restrict__ Bm,
    void* __restrict__ outv, int mode, int nbx)
{
    __shared__ u16 sA[2][8192], sB[2][8192];   // 64 KiB -> 2 blocks/CU

    const int tid  = threadIdx.x;
    const int lane = tid & 63, w = tid >> 6;
    const int wm   = w >> 2, wn = w & 3;            // wave grid 2 (M) x 4 (N)
    const int r15  = lane & 15, quad = lane >> 4;

    // T1: bijective XCD swizzle. nwg = 32*nbx, per-XCD chunk = 4*nbx
    const int bid = blockIdx.x;
    const int swz = (bid & 7) * (nbx << 2) + (bid >> 3);
    const int by  = swz / nbx;                       // M-tile 0..31 (A-panel)
    const int bx  = swz - by * nbx;                  // N-tile 0..nbx-1

    // staging: thread -> (row = tid&255, chunks c0 and c0+2), c0 = tid>>8
    const int srow = tid & 255;
    const int c0   = tid >> 8;
    const u16* gA = A  + (size_t)(by*256 + srow) * K_ + c0*8;
    const u16* gB = Bm + (size_t)(bx*256 + srow) * K_ + c0*8;
    // per-wave LDS segments (u16 units)
    const int segE = w * 512;
    const int segO = 4096 + w * 512;

    // fragment read bases (u16 index): chunk (row,kc) at slot kc*256+row
    const int aBase = (quad*256 + wm*128 + r15) * 8;
    const int bBase = (quad*256 + wn*64  + r15) * 8;

    const floatx4 fzero = {0.f, 0.f, 0.f, 0.f};
    floatx4 acc[8][4];
#pragma unroll
    for (int mi = 0; mi < 8; ++mi)
#pragma unroll
        for (int ni = 0; ni < 4; ++ni) acc[mi][ni] = fzero;

#define STAGE4(nbuf) do {                                                   \
        gll16(gA,      &sA[nbuf][segE]); gll16(gA + 16, &sA[nbuf][segO]);   \
        gll16(gB,      &sB[nbuf][segE]); gll16(gB + 16, &sB[nbuf][segO]);   \
        gA += 32; gB += 32; } while (0)

    // prologue: stage tiles 0 and 1; wait only for tile 0 (4 oldest of 8)
    STAGE4(0);
    STAGE4(1);
    asm volatile("s_waitcnt vmcnt(4)" ::: "memory");
    __builtin_amdgcn_s_barrier();

    const int NT = K_/32;
    int cur = 0;
    for (int kt = 0; kt < NT; ++kt) {
        // all 12 frag reads up front; compiler interleaves lgkm waits into MFMAs
        half8 a[8], b[4];
#pragma unroll
        for (int mi = 0; mi < 8; ++mi)
            a[mi] = *(const half8*)&sA[cur][aBase + mi*128];
#pragma unroll
        for (int ni = 0; ni < 4; ++ni)
            b[ni] = *(const half8*)&sB[cur][bBase + ni*128];

        __builtin_amdgcn_s_setprio(1);
#pragma unroll
        for (int mi = 0; mi < 4; ++mi)
#pragma unroll
            for (int ni = 0; ni < 4; ++ni)
                acc[mi][ni] = __builtin_amdgcn_mfma_f32_16x16x32_f16(a[mi], b[ni], acc[mi][ni], 0, 0, 0);
        __builtin_amdgcn_s_setprio(0);

        // all reads of buf[cur] complete in every wave -> safe to restage it
        asm volatile("s_waitcnt lgkmcnt(0)" ::: "memory");
        __builtin_amdgcn_sched_barrier(0);
        __builtin_amdgcn_s_barrier();
        __builtin_amdgcn_sched_barrier(0);
        if (kt < NT - 2) {
            STAGE4(cur);                       // tile kt+2 into the just-freed buffer
            __builtin_amdgcn_sched_barrier(0); // keep issue point ahead of MFMA tail
        }

        __builtin_amdgcn_s_setprio(1);
#pragma unroll
        for (int mi = 4; mi < 8; ++mi)
#pragma unroll
            for (int ni = 0; ni < 4; ++ni)
                acc[mi][ni] = __builtin_amdgcn_mfma_f32_16x16x32_f16(a[mi], b[ni], acc[mi][ni], 0, 0, 0);
        __builtin_amdgcn_s_setprio(0);

        // counted wait: oldest 4 = tile kt+1 (next buffer); tile kt+2 stays in flight
        if (kt < NT - 2)       asm volatile("s_waitcnt vmcnt(4)" ::: "memory");
        else if (kt == NT - 2) asm volatile("s_waitcnt vmcnt(0)" ::: "memory");
        if (kt < NT - 1) __builtin_amdgcn_s_barrier();
        cur ^= 1;
    }
#undef STAGE4

    // C/D layout: col = lane&15, row = quad*4 + reg  [m89/m91 verified]
    if (mode == 0) {
        u16* out = (u16*)outv;     // Q plane base; K,V contiguous 16777216 u16 apart
#pragma unroll
        for (int mi = 0; mi < 8; ++mi)
#pragma unroll
            for (int r = 0; r < 4; ++r) {
                int m  = by*256 + wm*128 + mi*16 + quad*4 + r;
                int bb = m >> 8, ss = m & 255;
#pragma unroll
                for (int ni = 0; ni < 4; ++ni) {
                    int n = bx*256 + wn*64 + ni*16 + r15;
                    int which = n >> 11, rem = n & 2047;
                    int h = rem >> 7, d = rem & 127;
                    out[(size_t)which*16777216 +
                        (((size_t)(bb*NH_ + h)) * S_ + ss) * HD_ + d] = f2h(acc[mi][ni][r]);
                }
            }
    } else {
        float* out = (float*)outv;                   // [M, 2048]
#pragma unroll
        for (int mi = 0; mi < 8; ++mi)
#pragma unroll
            for (int r = 0; r < 4; ++r) {
                int m = by*256 + wm*128 + mi*16 + quad*4 + r;
                size_t base = (size_t)m * H_ + bx*256 + wn*64 + r15;
#pragma unroll
                for (int ni = 0; ni < 4; ++ni)
                    out[base + ni*16] = acc[mi][ni][r];
            }
    }
}

// ---------------------------------------------------------------------------
// RoPE in-place on fp16 q,k in [B,NH,S,HD]; pair (i, i+64). Accurate cosf/sinf.
// ---------------------------------------------------------------------------
__global__ __launch_bounds__(256) void rope_f16(u16* __restrict__ q, u16* __restrict__ k)
{
    int idx = blockIdx.x * 256 + threadIdx.x;       // pair index
    u16* p = blockIdx.y ? k : q;
    int i  = idx & 63;
    int s  = (idx >> 6) & (S_ - 1);
    int bh = idx >> 14;
    size_t base = ((size_t)bh * S_ + s) * HD_;
    float f = expf((float)i * -0.14391156831212788f);   // 10000^(-i/64)
    float ang = (float)s * f;
    float c = cosf(ang), sn = sinf(ang);
    float x0 = h2f(p[base + i]), x1 = h2f(p[base + i + 64]);
    p[base + i]      = f2h(x0 * c - x1 * sn);
    p[base + i + 64] = f2h(x1 * c + x0 * sn);
}

// ---------------------------------------------------------------------------
// Attention, fp16 MFMA. Block = 256 thr (4 waves) handles (b,h) x 64 q-rows.
// Scores kept in C-layout registers; softmax via 16-lane shuffle; P -> LDS
// (plane-major) -> A-operand for PV.  Output: single fp16 [M, 2048].
// ---------------------------------------------------------------------------
#define SCALE 0.08838834764831845f

__global__ __launch_bounds__(256) void attn_mfma(
    const u16* __restrict__ Q, const u16* __restrict__ K, const u16* __restrict__ V,
    u16* __restrict__ O)
{
    __shared__ u16 shQK[16384];
    __shared__ u16 shV[8192];
    u16* Qs = shQK;            // planes [16][64] chunks of 8 fp16
    u16* Ks = shQK + 8192;     // planes [16][64]
    u16* Pb = shQK;            // planes [32][64]  (after Qs/Ks dead)

    const int tid = threadIdx.x;
    const int lane = tid & 63, w = tid >> 6;
    const int r15 = lane & 15, quad = lane >> 4;
    const int bh = blockIdx.x;
    const int q0 = blockIdx.y << 6;
    const int wq = w * 16;

    const u16* Qg = Q + ((size_t)bh * S_ + q0) * HD_;
    const u16* Kg = K + (size_t)bh * S_ * HD_;
    const u16* Vg = V + (size_t)bh * S_ * HD_;

    // stage Q tile 64x128 -> plane-major
#pragma unroll
    for (int p = 0; p < 4; ++p) {
        int task = tid + (p << 8);
        int r = task & 63, c = task >> 6;
        *(uint4*)&Qs[(c*64 + r)*8] = *(const uint4*)&Qg[(size_t)r*HD_ + c*8];
    }

    const floatx4 fzero = {0.f, 0.f, 0.f, 0.f};
    floatx4 sc[4][4];                          // [kt][ni]; rows wq+quad*4+reg
    for (int kt = 0; kt < 4; ++kt) {
        __syncthreads();
#pragma unroll
        for (int p = 0; p < 4; ++p) {
            int task = tid + (p << 8);
            int r = task & 63, c = task >> 6;
            *(uint4*)&Ks[(c*64 + r)*8] = *(const uint4*)&Kg[(size_t)(kt*64 + r)*HD_ + c*8];
        }
        __syncthreads();
#pragma unroll
        for (int ni = 0; ni < 4; ++ni) sc[kt][ni] = fzero;
#pragma unroll
        for (int ks = 0; ks < 4; ++ks) {
            half8 a = *(const half8*)&Qs[((ks*4 + quad)*64 + wq + r15)*8];
#pragma unroll
            for (int ni = 0; ni < 4; ++ni) {
                half8 b = *(const half8*)&Ks[((ks*4 + quad)*64 + ni*16 + r15)*8];
                sc[kt][ni] = __builtin_amdgcn_mfma_f32_16x16x32_f16(a, b, sc[kt][ni], 0, 0, 0);
            }
        }
    }
    __syncthreads();   // all Qs/Ks reads complete before Pb overwrites them

    // ---- softmax in registers (rows wq+quad*4+r; 16 col-lanes via shuffle) ----
#pragma unroll
    for (int kt = 0; kt < 4; ++kt)
#pragma unroll
        for (int ni = 0; ni < 4; ++ni) sc[kt][ni] *= SCALE;

    float rinv4[4], mrow4[4];
#pragma unroll
    for (int r = 0; r < 4; ++r) {
        float m = -1e30f;
#pragma unroll
        for (int kt = 0; kt < 4; ++kt)
#pragma unroll
            for (int ni = 0; ni < 4; ++ni) m = fmaxf(m, sc[kt][ni][r]);
#pragma unroll
        for (int o = 1; o < 16; o <<= 1) m = fmaxf(m, __shfl_xor(m, o));
        mrow4[r] = m;
    }
#pragma unroll
    for (int r = 0; r < 4; ++r) {
        float ssum = 0.f;
#pragma unroll
        for (int kt = 0; kt < 4; ++kt)
#pragma unroll
            for (int ni = 0; ni < 4; ++ni) {
                float e = __expf(sc[kt][ni][r] - mrow4[r]);
                sc[kt][ni][r] = e;
                ssum += e;
            }
#pragma unroll
        for (int o = 1; o < 16; o <<= 1) ssum += __shfl_xor(ssum, o);
        rinv4[r] = 1.f / ssum;
    }
    // write P fp16 -> Pb plane-major: elem(row,col) at chunk (col>>3)*64+row
#pragma unroll
    for (int r = 0; r < 4; ++r) {
        int row = wq + quad*4 + r;
#pragma unroll
        for (int kt = 0; kt < 4; ++kt)
#pragma unroll
            for (int ni = 0; ni < 4; ++ni) {
                int col = kt*64 + ni*16 + r15;
                Pb[((col >> 3)*64 + row)*8 + (col & 7)] = f2h(sc[kt][ni][r] * rinv4[r]);
            }
    }

    // ---- O = P V ----
    floatx4 oacc[8];
#pragma unroll
    for (int di = 0; di < 8; ++di) oacc[di] = fzero;

    for (int vt = 0; vt < 4; ++vt) {
        __syncthreads();
        // stage V tile transposed: Vt planes [8][128] chunks; elem(d,s') at chunk (s'>>3)*128+d
#pragma unroll
        for (int p = 0; p < 4; ++p) {
            int task = tid + (p << 8);
            int r = task & 63, dc = task >> 6;          // s' = r, d-chunk dc
            ushort8 v = *(const ushort8*)&Vg[(size_t)(vt*64 + r)*HD_ + dc*8];
#pragma unroll
            for (int j = 0; j < 8; ++j)
                shV[(((r >> 3)*128) + dc*8 + j)*8 + (r & 7)] = v[j];
        }
        __syncthreads();
#pragma unroll
        for (int ks = 0; ks < 2; ++ks) {
            int colbase = vt*64 + ks*32 + quad*8;
            half8 a = *(const half8*)&Pb[((colbase >> 3)*64 + wq + r15)*8];
            int sp = ks*32 + quad*8;
#pragma unroll
            for (int di = 0; di < 8; ++di) {
                half8 b = *(const half8*)&shV[((sp >> 3)*128 + di*16 + r15)*8];
                oacc[di] = __builtin_amdgcn_mfma_f32_16x16x32_f16(a, b, oacc[di], 0, 0, 0);
            }
        }
    }

    // epilogue: att[m][n] -> fp16, m = b*256+s, n = h*128 + d
    const int brow = bh >> 4, h = bh & 15;
#pragma unroll
    for (int r = 0; r < 4; ++r) {
        size_t base = ((size_t)(brow*S_ + q0 + wq + quad*4 + r)) * H_ + h*128 + r15;
#pragma unroll
        for (int di = 0; di < 8; ++di)
            O[base + di*16] = f2h(oacc[di][r]);
    }
}

// ---------------------------------------------------------------------------
extern "C" void kernel_launch(void* const* d_in, const int* in_sizes, int n_in,
                              void* d_out, int out_size, void* d_ws, size_t ws_size,
                              hipStream_t stream)
{
    const float* X  = (const float*)d_in[0];
    const float* Wp[4] = {(const float*)d_in[1], (const float*)d_in[2],
                          (const float*)d_in[3], (const float*)d_in[4]};   // q,k,v,o
    float* outp = (float*)d_out;

    char* ws = (char*)d_ws;
    u16* Xh  = (u16*)ws;                          //  33.5 MB [M,2048] fp16
    u16* W16 = (u16*)(ws + 33554432);             //  4 x 8.39 MB fp16 (q,k,v,o stacked)
    u16* Qh  = (u16*)(ws + 67108864);             //  33.5 MB [B,NH,S,HD]
    u16* Kh  = (u16*)(ws + 100663296);            //  (Q,K,V contiguous!)
    u16* Vh  = (u16*)(ws + 134217728);            //  total 168 MB
    u16* Ah  = Xh;                                // alias: X dead after projections

    cvt16<<<(M_*H_/4)/256, 256, 0, stream>>>(X, Xh, M_*H_/4);
    for (int i = 0; i < 4; ++i)
        cvt16<<<(H_*H_/4)/256, 256, 0, stream>>>(Wp[i], W16 + (size_t)i*4194304, H_*H_/4);

    // fused QKV projection: B = [Wq;Wk;Wv] (contiguous), N = 6144, grid 768
    // 64 KiB LDS -> 2 blocks resident/CU; 768 blocks = 3 generations over 2 slots
    gemm_f16<<<768, 512, 0, stream>>>(Xh, W16, Qh, 0, 24);
    rope_f16<<<dim3(32768, 2), 256, 0, stream>>>(Qh, Kh);
    attn_mfma<<<dim3(B_*NH_, 4), 256, 0, stream>>>(Qh, Kh, Vh, Ah);
    gemm_f16<<<256, 512, 0, stream>>>(Ah, W16 + 3*4194304, outp, 1, 8);
}